// Round 2
// baseline (753.980 us; speedup 1.0000x reference)
//
#include <hip/hip_runtime.h>

// Problem constants (from reference)
constexpr int B     = 16;
constexpr int H     = 32;
constexpr int KVH   = 8;
constexpr int D     = 128;
constexpr int PAGE  = 16;
constexpr int LMAX  = 1024;
constexpr int GROUPS = H / KVH;          // 4 heads share one kv head
constexpr int CSTRIDE = KVH * PAGE * D;  // stride of the K/V axis = 16384 elems

// One block per (b,h). 256 threads = 8 groups of 32 lanes.
// Each 32-lane group loads one 512B K/V row per iteration as 32 x float4
// (single fully-coalesced transaction per row). Unroll 4 keeps ~4 gathers
// in flight per wave to hide HBM latency at low occupancy (8 waves/CU).
__global__ __launch_bounds__(256) void sparse_paged_decode_kernel(
    const float* __restrict__ q,
    const float* __restrict__ kv,
    const int*   __restrict__ indptr,
    const int*   __restrict__ page_indices,
    const int*   __restrict__ sind,
    const int*   __restrict__ snnz,
    float*       __restrict__ out)
{
    const int bh  = blockIdx.x;          // 0..511
    const int b   = bh >> 5;             // / H
    const int h   = bh & 31;             // % H
    const int kvh = h >> 2;              // / GROUPS
    const int tid = threadIdx.x;
    const int g   = tid >> 5;            // row-group 0..7
    const int lg  = tid & 31;            // lane within group

    __shared__ float s_scores[LMAX];
    __shared__ int   s_row[LMAX];        // K-row element offset (V = +CSTRIDE)
    __shared__ float s_red[8];
    __shared__ float s_vacc[8 * D];

    const int nnz    = snnz[bh];
    const int lcount = nnz < LMAX ? nnz : LMAX;
    float* outp = out + bh * D;

    if (lcount <= 0) {
        // reference zeroes output when nnz == 0
        if (tid < D) outp[tid] = 0.0f;
        return;
    }

    const int ip = indptr[b];
    // q fragment: lane lg owns q[4*lg .. 4*lg+3] of this head
    const float4 q4 = reinterpret_cast<const float4*>(q + (size_t)bh * D)[lg];

    // ---- Phase 1: scores[l] = (q . K[l]) * scale ----
    const int sbase = bh * LMAX;
    #pragma unroll 4
    for (int l = g; l < lcount; l += 8) {
        const int idx     = sind[sbase + l];                  // broadcast load
        const int page_id = page_indices[ip + (idx >> 4)];
        const int row     = (((page_id * 2) * KVH + kvh) * PAGE + (idx & 15)) * D;
        const float4 k4   = reinterpret_cast<const float4*>(kv + row)[lg];
        float p = k4.x * q4.x + k4.y * q4.y + k4.z * q4.z + k4.w * q4.w;
        // reduce across the 32-lane group (masks <= 16 never cross 32-boundary)
        #pragma unroll
        for (int m = 16; m; m >>= 1) p += __shfl_xor(p, m);
        if (lg == 0) {
            s_scores[l] = p * 0.08838834764831845f;  // 1/sqrt(128)
            s_row[l]    = row;
        }
    }
    __syncthreads();

    // ---- Phase 2: softmax over s_scores[0..lcount) ----
    float mx = -INFINITY;
    for (int l = tid; l < lcount; l += 256) mx = fmaxf(mx, s_scores[l]);
    #pragma unroll
    for (int m = 32; m; m >>= 1) mx = fmaxf(mx, __shfl_xor(mx, m));
    if ((tid & 63) == 0) s_red[tid >> 6] = mx;
    __syncthreads();
    mx = fmaxf(fmaxf(s_red[0], s_red[1]), fmaxf(s_red[2], s_red[3]));

    float sum = 0.0f;
    for (int l = tid; l < lcount; l += 256) {
        const float w = __expf(s_scores[l] - mx);
        s_scores[l] = w;
        sum += w;
    }
    #pragma unroll
    for (int m = 32; m; m >>= 1) sum += __shfl_xor(sum, m);
    if ((tid & 63) == 0) s_red[4 + (tid >> 6)] = sum;
    __syncthreads();
    const float inv = 1.0f / (s_red[4] + s_red[5] + s_red[6] + s_red[7]);

    // ---- Phase 3: out = sum_l w[l] * V[l] ----
    float4 acc = make_float4(0.f, 0.f, 0.f, 0.f);
    #pragma unroll 4
    for (int l = g; l < lcount; l += 8) {
        const float  w  = s_scores[l];
        const float4 v4 = reinterpret_cast<const float4*>(kv + (s_row[l] + CSTRIDE))[lg];
        acc.x += w * v4.x; acc.y += w * v4.y; acc.z += w * v4.z; acc.w += w * v4.w;
    }
    reinterpret_cast<float4*>(s_vacc)[g * 32 + lg] = acc;
    __syncthreads();

    if (tid < D) {
        float t = 0.0f;
        #pragma unroll
        for (int gg = 0; gg < 8; ++gg) t += s_vacc[gg * D + tid];
        outp[tid] = t * inv;
    }
}

extern "C" void kernel_launch(void* const* d_in, const int* in_sizes, int n_in,
                              void* d_out, int out_size, void* d_ws, size_t ws_size,
                              hipStream_t stream) {
    const float* q            = (const float*)d_in[0];
    const float* kv           = (const float*)d_in[1];
    const int*   indptr       = (const int*)d_in[2];
    const int*   page_indices = (const int*)d_in[3];
    const int*   sind         = (const int*)d_in[4];
    const int*   snnz         = (const int*)d_in[5];
    float*       out          = (float*)d_out;

    sparse_paged_decode_kernel<<<B * H, 256, 0, stream>>>(
        q, kv, indptr, page_indices, sind, snnz, out);
}